// Round 3
// baseline (1177.652 us; speedup 1.0000x reference)
//
#include <hip/hip_runtime.h>
#include <math.h>

#define BB 4
#define NN 4096
#define DEGQ 16
#define DDIM 128
#define EDIM 256
#define EE (NN*DEGQ)   // 65536

// ws layout (in floats)
#define WS_XN     0
#define WS_UVPQ   (WS_XN + BB*NN*DDIM)            // per-node u,v,p,q: [B*N][768]
#define WS_SCORES (WS_UVPQ + (size_t)BB*NN*768)
#define WS_THR    (WS_SCORES + (size_t)BB*EE)     // 8 floats
#define WS_SELP   (WS_THR + 8)                    // 4 u32
#define WS_SELR   (WS_SELP + 4)                   // 4 i32
#define WS_GHIST  (WS_SELR + 4)                   // 1024 u32
#define WS_BN     (WS_GHIST + 1024)               // 768 floats

// ---------------- normalize: one wave per node row ----------------
__global__ void k_norm(const float* __restrict__ nf, float* __restrict__ xn) {
    int wave = (blockIdx.x * blockDim.x + threadIdx.x) >> 6;
    int lane = threadIdx.x & 63;
    if (wave >= BB * NN) return;
    const float* row = nf + (size_t)wave * DDIM;
    float2 v = *(const float2*)(row + 2 * lane);
    float ss = v.x * v.x + v.y * v.y;
#pragma unroll
    for (int d = 32; d; d >>= 1) ss += __shfl_xor(ss, d, 64);
    float n = fmaxf(sqrtf(ss), 1e-12f);
    float inv = 1.0f / n;
    float2 o; o.x = v.x * inv; o.y = v.y * inv;
    *(float2*)(xn + (size_t)wave * DDIM + 2 * lane) = o;
}

// ---------------- BN constants + select-state init ----------------
__global__ void k_prep(const float* g1, const float* be1, const float* m1, const float* v1,
                       const float* g2, const float* be2, const float* m2, const float* v2,
                       float* bn, unsigned* ghist, unsigned* selp, int* selr) {
    int c = threadIdx.x;
    ghist[c] = 0u; ghist[256 + c] = 0u; ghist[512 + c] = 0u; ghist[768 + c] = 0u;
    if (c < 4) { selp[c] = 0u; selr[c] = EE / 2 - 1; }
    if (c < 256) {
        float s = g1[c] / sqrtf(v1[c] + 1e-5f);
        bn[c] = s; bn[256 + c] = be1[c] - m1[c] * s;
    }
    if (c < 128) {
        float s = g2[c] / sqrtf(v2[c] + 1e-5f);
        bn[512 + c] = s; bn[640 + c] = be2[c] - m2[c] * s;
    }
}

// ---------------- per-node u,v,p,q = xn @ {Wa1_top, Wa1_bot, W1a, W1b} ----------------
__global__ void k_uvpq(const float* __restrict__ xn, const float* __restrict__ Wa1,
                       const float* __restrict__ W1, float* __restrict__ uvpq) {
    int chunk = blockIdx.y;
    const float* wbase; int wstride; int ocol;
    switch (chunk) {
        case 0: wbase = Wa1;                 wstride = 128; ocol = 0;   break;
        case 1: wbase = Wa1 + 128 * 128;     wstride = 128; ocol = 128; break;
        case 2: wbase = W1;                  wstride = 256; ocol = 256; break;
        case 3: wbase = W1 + 128;            wstride = 256; ocol = 384; break;
        case 4: wbase = W1 + 128 * 256;      wstride = 256; ocol = 512; break;
        default: wbase = W1 + 128 * 256 + 128; wstride = 256; ocol = 640; break;
    }
    int wv = threadIdx.x >> 6, lane = threadIdx.x & 63;
    int nodebase = blockIdx.x * 32 + wv * 8;
    const float* xrow[8];
#pragma unroll
    for (int j = 0; j < 8; ++j) xrow[j] = xn + (size_t)(nodebase + j) * DDIM;
    float acc0[8] = {}, acc1[8] = {};
#pragma unroll 4
    for (int k = 0; k < 128; ++k) {
        float w0 = wbase[k * wstride + lane];
        float w1 = wbase[k * wstride + 64 + lane];
#pragma unroll
        for (int j = 0; j < 8; ++j) {
            float a = xrow[j][k];
            acc0[j] = fmaf(a, w0, acc0[j]);
            acc1[j] = fmaf(a, w1, acc1[j]);
        }
    }
#pragma unroll
    for (int j = 0; j < 8; ++j) {
        float* orow = uvpq + (size_t)(nodebase + j) * 768 + ocol;
        orow[lane] = acc0[j];
        orow[64 + lane] = acc1[j];
    }
}

// ---------------- fused edge pipeline: lane = edge, 64 edges/block, 8 waves split cols --
// LDS: r1 [128][64] (h1 -> gT -> h2T_hi), r2 [128][64] (aT -> h2T_lo -> prodT)
__global__ __launch_bounds__(512, 4) void
k_edge(const float* __restrict__ xn, const float* __restrict__ uvpq,
       const float* __restrict__ Wa2, const float* __restrict__ ba1,
       const float* __restrict__ ba2, const float* __restrict__ W1,
       const float* __restrict__ b1, const float* __restrict__ W2,
       const float* __restrict__ b2, const float* __restrict__ W3,
       const float* __restrict__ b3, const int* __restrict__ src,
       const int* __restrict__ tgt, const float* __restrict__ bn,
       float* __restrict__ scores) {
    __shared__ float r1[128 * 64];
    __shared__ float r2[128 * 64];
    int tid = threadIdx.x;
    int lane = tid & 63;
    int wvs = __builtin_amdgcn_readfirstlane(tid >> 6);   // wave-uniform scalar
    int b = blockIdx.y;
    int T0 = blockIdx.x * 64;
    int se = src[(size_t)b * EE + T0 + lane];
    int te = tgt[(size_t)b * EE + T0 + lane];
    const float* uv = uvpq + (size_t)b * NN * 768;
    const float* xb = xn + (size_t)b * NN * DDIM;
    const float* up = uv + (size_t)se * 768;
    const float* vp = uv + (size_t)te * 768 + 128;
    int cb = wvs * 16;

    // ---- stage h1 rows k in [16*wvs, 16*wvs+16): h1[k][e] = relu(u_s[k]+v_t[k]+ba1[k])
    {
        const float4* u4 = (const float4*)(up + cb);
        const float4* v4 = (const float4*)(vp + cb);
#pragma unroll
        for (int q = 0; q < 4; ++q) {
            float4 uu = u4[q], vv = v4[q];
            float4 bb = *(const float4*)(ba1 + cb + 4 * q);   // uniform -> s_load
            r1[(cb + 4 * q + 0) * 64 + lane] = fmaxf(uu.x + vv.x + bb.x, 0.0f);
            r1[(cb + 4 * q + 1) * 64 + lane] = fmaxf(uu.y + vv.y + bb.y, 0.0f);
            r1[(cb + 4 * q + 2) * 64 + lane] = fmaxf(uu.z + vv.z + bb.z, 0.0f);
            r1[(cb + 4 * q + 3) * 64 + lane] = fmaxf(uu.w + vv.w + bb.w, 0.0f);
        }
    }
    __syncthreads();

    // ---- GEMV1: a[c] = sum_k h1[k]*Wa2[k][c], cols cb..cb+15; aT -> r2
    {
        float acc[16] = {};
#pragma unroll 2
        for (int k = 0; k < 128; ++k) {
            float h = r1[k * 64 + lane];
            const float* wr = Wa2 + k * 128 + cb;   // uniform row
#pragma unroll
            for (int i = 0; i < 16; ++i) acc[i] = fmaf(h, wr[i], acc[i]);
        }
#pragma unroll
        for (int i = 0; i < 16; ++i) r2[(cb + i) * 64 + lane] = acc[i] + ba2[cb + i];
    }
    __syncthreads();

    // ---- softmax per-lane (replicated in every wave; exact old tree order)
    float m, inv;
    {
        float mm[64];
#pragma unroll
        for (int c = 0; c < 64; ++c)
            mm[c] = fmaxf(r2[c * 64 + lane], r2[(c + 64) * 64 + lane]);
#pragma unroll
        for (int d = 32; d; d >>= 1)
#pragma unroll
            for (int c = 0; c < d; ++c) mm[c] = fmaxf(mm[c], mm[c + d]);
        m = mm[0];
        float z[64];
#pragma unroll
        for (int c = 0; c < 64; ++c)
            z[c] = expf(r2[c * 64 + lane] - m) + expf(r2[(c + 64) * 64 + lane] - m);
#pragma unroll
        for (int d = 32; d; d >>= 1)
#pragma unroll
            for (int c = 0; c < d; ++c) z[c] = z[c] + z[c + d];
        inv = 1.0f / z[0];
    }
    // ---- g[c] = |sf-tf|[c] * p[c] * inv for wave's cols; gT -> r1 (h1 dead)
    {
        const float4* xs4 = (const float4*)(xb + (size_t)se * DDIM + cb);
        const float4* xt4 = (const float4*)(xb + (size_t)te * DDIM + cb);
#pragma unroll
        for (int q = 0; q < 4; ++q) {
            float4 xs = xs4[q], xt = xt4[q];
            float dv[4] = {fabsf(xs.x - xt.x), fabsf(xs.y - xt.y),
                           fabsf(xs.z - xt.z), fabsf(xs.w - xt.w)};
#pragma unroll
            for (int r = 0; r < 4; ++r) {
                int c = cb + 4 * q + r;
                float p = expf(r2[c * 64 + lane] - m);
                r1[c * 64 + lane] = dv[r] * p * inv;
            }
        }
    }
    __syncthreads();

    const float* W1c = W1 + 256 * 256;
    const float* pr = uv + (size_t)se * 768 + 256;
    const float* qr = uv + (size_t)te * 768 + 512;

    // ---- GEMV2 phase A: cols cb (0..127); h2T_lo -> r2 (aT dead)
    {
        float acc[16] = {};
#pragma unroll 2
        for (int k = 0; k < 128; ++k) {
            float g = r1[k * 64 + lane];
            const float* wr = W1c + k * 256 + cb;
#pragma unroll
            for (int i = 0; i < 16; ++i) acc[i] = fmaf(g, wr[i], acc[i]);
        }
        float4 p4[4], q4[4];
#pragma unroll
        for (int q = 0; q < 4; ++q) {
            p4[q] = *(const float4*)(pr + cb + 4 * q);
            q4[q] = *(const float4*)(qr + cb + 4 * q);
        }
#pragma unroll
        for (int i = 0; i < 16; ++i) {
            int c = cb + i;
            float pv = ((const float*)p4)[i], qv = ((const float*)q4)[i];
            float y = acc[i] + pv + qv + b1[c];
            r2[c * 64 + lane] = fmaxf(fmaf(y, bn[c], bn[256 + c]), 0.0f);
        }
    }
    // ---- GEMV2 phase B: cols 128+cb; hold in regs, then h2T_hi -> r1 after barrier
    float h2b[16];
    {
        int cB = 128 + cb;
        float acc[16] = {};
#pragma unroll 2
        for (int k = 0; k < 128; ++k) {
            float g = r1[k * 64 + lane];
            const float* wr = W1c + k * 256 + cB;
#pragma unroll
            for (int i = 0; i < 16; ++i) acc[i] = fmaf(g, wr[i], acc[i]);
        }
        float4 p4[4], q4[4];
#pragma unroll
        for (int q = 0; q < 4; ++q) {
            p4[q] = *(const float4*)(pr + cB + 4 * q);
            q4[q] = *(const float4*)(qr + cB + 4 * q);
        }
#pragma unroll
        for (int i = 0; i < 16; ++i) {
            int c = cB + i;
            float pv = ((const float*)p4)[i], qv = ((const float*)q4)[i];
            float y = acc[i] + pv + qv + b1[c];
            h2b[i] = fmaxf(fmaf(y, bn[c], bn[256 + c]), 0.0f);
        }
    }
    __syncthreads();   // all gT reads done
#pragma unroll
    for (int i = 0; i < 16; ++i) r1[(cb + i) * 64 + lane] = h2b[i];
    __syncthreads();

    // ---- GEMV3: k 0..127 from r2, k 128..255 from r1; cols cb (of 128)
    {
        float acc[16] = {};
#pragma unroll 2
        for (int k = 0; k < 128; ++k) {
            float h = r2[k * 64 + lane];
            const float* wr = W2 + k * 128 + cb;
#pragma unroll
            for (int i = 0; i < 16; ++i) acc[i] = fmaf(h, wr[i], acc[i]);
        }
#pragma unroll 2
        for (int k = 128; k < 256; ++k) {
            float h = r1[(k - 128) * 64 + lane];
            const float* wr = W2 + k * 128 + cb;
#pragma unroll
            for (int i = 0; i < 16; ++i) acc[i] = fmaf(h, wr[i], acc[i]);
        }
        float prod[16];
#pragma unroll
        for (int i = 0; i < 16; ++i) {
            int c = cb + i;
            float h3 = fmaxf(fmaf(acc[i] + b2[c], bn[512 + c], bn[640 + c]), 0.0f);
            prod[i] = h3 * W3[c];
        }
        __syncthreads();   // all r2 reads done
#pragma unroll
        for (int i = 0; i < 16; ++i) r2[(cb + i) * 64 + lane] = prod[i];
    }
    __syncthreads();

    // ---- logit tree (exact old pairing) + sigmoid; wave 0 stores
    {
        float z[64];
#pragma unroll
        for (int c = 0; c < 64; ++c)
            z[c] = r2[c * 64 + lane] + r2[(c + 64) * 64 + lane];
#pragma unroll
        for (int d = 32; d; d >>= 1)
#pragma unroll
            for (int c = 0; c < d; ++c) z[c] = z[c] + z[c + d];
        float sc = 1.0f / (1.0f + expf(-(z[0] + b3[0])));
        if (wvs == 0) scores[(size_t)b * EE + T0 + lane] = sc;
    }
}

// ---------------- parallel radix-select: histogram pass ----------------
__global__ void k_hist(const float* __restrict__ scores, const unsigned* __restrict__ selp,
                       unsigned* __restrict__ ghist, int pass) {
    __shared__ unsigned h[256];
    int b = blockIdx.y;
    h[threadIdx.x] = 0u;
    __syncthreads();
    unsigned pref = selp[b];
    unsigned mask = (pass == 3) ? 0u : (0xFFFFFFFFu << ((pass + 1) * 8));
    const unsigned* sb = (const unsigned*)(scores + (size_t)b * EE);
    int base = blockIdx.x * 2048;
    for (int i = base + threadIdx.x; i < base + 2048; i += 256) {
        unsigned u = sb[i];
        if ((u & mask) == pref) atomicAdd(&h[(u >> (pass * 8)) & 255], 1u);
    }
    __syncthreads();
    unsigned v = h[threadIdx.x];
    if (v) atomicAdd(&ghist[b * 256 + threadIdx.x], v);
}

// ---------------- parallel radix-select: pick digit, reset hist ----------------
__global__ void k_pick(unsigned* __restrict__ ghist, unsigned* __restrict__ selp,
                       int* __restrict__ selr, float* __restrict__ thr, int pass) {
    __shared__ unsigned sh[256];
    int b = blockIdx.x;
    unsigned* gh = ghist + b * 256;
    sh[threadIdx.x] = gh[threadIdx.x];
    __syncthreads();
    if (threadIdx.x == 0) {
        unsigned r = (unsigned)selr[b], cum = 0;
        for (int x = 0; x < 256; ++x) {
            unsigned c = sh[x];
            if (cum + c > r) {
                selp[b] |= (unsigned)x << (pass * 8);
                selr[b] = (int)(r - cum);
                break;
            }
            cum += c;
        }
        if (pass == 0) thr[b] = __uint_as_float(selp[b]);
    }
    __syncthreads();
    gh[threadIdx.x] = 0u;
}

// ---------------- threshold + per-group repair + scatter ----------------
__global__ void k_scatter(const float* __restrict__ scores, const float* __restrict__ thr,
                          const int* __restrict__ src, const int* __restrict__ tgt,
                          const int* __restrict__ mep, float* __restrict__ out) {
    int gid = blockIdx.x * 256 + threadIdx.x;
    int b = gid >> 16;
    int lane = threadIdx.x & 63;
    int j = lane & 15;
    float s = scores[gid];
    float t = thr[b];
    bool above = (s >= t);
    unsigned long long bal = __ballot(above);
    int sub = lane >> 4;
    unsigned int mask16 = (unsigned int)((bal >> (sub * 16)) & 0xFFFFull);
    int active = __popc(mask16);
    int rank = 0;
#pragma unroll
    for (int j2 = 0; j2 < 16; ++j2) {
        float sv = __shfl(s, (lane & 48) + j2, 64);
        rank += (sv > s || (sv == s && j2 < j)) ? 1 : 0;
    }
    int me = *mep;
    int need = (active < me) ? min(me - active, DEGQ) : 0;
    bool keep = above || (rank < need);
    float wgt = keep ? s : 0.0f;
    out[(size_t)b * NN * NN + (size_t)src[gid] * NN + tgt[gid]] = wgt;
}

extern "C" void kernel_launch(void* const* d_in, const int* in_sizes, int n_in,
                              void* d_out, int out_size, void* d_ws, size_t ws_size,
                              hipStream_t stream) {
    const float* nf  = (const float*)d_in[0];
    const int*   src = (const int*)d_in[1];
    const int*   tgt = (const int*)d_in[2];
    const float* Wa1 = (const float*)d_in[3];
    const float* ba1 = (const float*)d_in[4];
    const float* Wa2 = (const float*)d_in[5];
    const float* ba2 = (const float*)d_in[6];
    const float* W1  = (const float*)d_in[7];
    const float* b1  = (const float*)d_in[8];
    const float* g1  = (const float*)d_in[9];
    const float* be1 = (const float*)d_in[10];
    const float* m1  = (const float*)d_in[11];
    const float* v1  = (const float*)d_in[12];
    const float* W2  = (const float*)d_in[13];
    const float* b2  = (const float*)d_in[14];
    const float* g2  = (const float*)d_in[15];
    const float* be2 = (const float*)d_in[16];
    const float* m2  = (const float*)d_in[17];
    const float* v2  = (const float*)d_in[18];
    const float* W3  = (const float*)d_in[19];
    const float* b3  = (const float*)d_in[20];
    const int*   mep = (const int*)d_in[21];

    float* ws = (float*)d_ws;
    float*    xn     = ws + WS_XN;
    float*    uvpq   = ws + WS_UVPQ;
    float*    scores = ws + WS_SCORES;
    float*    thrb   = ws + WS_THR;
    unsigned* selp   = (unsigned*)(ws + WS_SELP);
    int*      selr   = (int*)(ws + WS_SELR);
    unsigned* ghist  = (unsigned*)(ws + WS_GHIST);
    float*    bn     = ws + WS_BN;
    float*    out    = (float*)d_out;

    hipMemsetAsync(d_out, 0, (size_t)out_size * sizeof(float), stream);
    k_prep<<<1, 256, 0, stream>>>(g1, be1, m1, v1, g2, be2, m2, v2, bn, ghist, selp, selr);
    k_norm<<<(BB * NN) / 4, 256, 0, stream>>>(nf, xn);
    k_uvpq<<<dim3((BB * NN) / 32, 6), 256, 0, stream>>>(xn, Wa1, W1, uvpq);
    k_edge<<<dim3(EE / 64, BB), 512, 0, stream>>>(xn, uvpq, Wa2, ba1, ba2, W1, b1,
                                                  W2, b2, W3, b3, src, tgt, bn, scores);
    for (int pass = 3; pass >= 0; --pass) {
        k_hist<<<dim3(32, BB), 256, 0, stream>>>(scores, selp, ghist, pass);
        k_pick<<<BB, 256, 0, stream>>>(ghist, selp, selr, thrb, pass);
    }
    k_scatter<<<(BB * EE) / 256, 256, 0, stream>>>(scores, thrb, src, tgt, mep, out);
}

// Round 4
// 864.373 us; speedup vs baseline: 1.3624x; 1.3624x over previous
//
#include <hip/hip_runtime.h>
#include <math.h>

#define BB 4
#define NN 4096
#define DEGQ 16
#define DDIM 128
#define EDIM 256
#define EE (NN*DEGQ)   // 65536

// ws layout (in floats)
#define WS_XN     0
#define WS_UVPQ   (WS_XN + BB*NN*DDIM)            // per-node u,v,p,q: [B*N][768]
#define WS_SCORES (WS_UVPQ + (size_t)BB*NN*768)
#define WS_THR    (WS_SCORES + (size_t)BB*EE)     // 8 floats
#define WS_SELP   (WS_THR + 8)                    // 4 u32
#define WS_SELR   (WS_SELP + 4)                   // 4 i32
#define WS_GHIST  (WS_SELR + 4)                   // 1024 u32
#define WS_BN     (WS_GHIST + 1024)               // 768 floats

// ---------------- normalize: one wave per node row ----------------
__global__ void k_norm(const float* __restrict__ nf, float* __restrict__ xn) {
    int wave = (blockIdx.x * blockDim.x + threadIdx.x) >> 6;
    int lane = threadIdx.x & 63;
    if (wave >= BB * NN) return;
    const float* row = nf + (size_t)wave * DDIM;
    float2 v = *(const float2*)(row + 2 * lane);
    float ss = v.x * v.x + v.y * v.y;
#pragma unroll
    for (int d = 32; d; d >>= 1) ss += __shfl_xor(ss, d, 64);
    float n = fmaxf(sqrtf(ss), 1e-12f);
    float inv = 1.0f / n;
    float2 o; o.x = v.x * inv; o.y = v.y * inv;
    *(float2*)(xn + (size_t)wave * DDIM + 2 * lane) = o;
}

// ---------------- BN constants + select-state init ----------------
__global__ void k_prep(const float* g1, const float* be1, const float* m1, const float* v1,
                       const float* g2, const float* be2, const float* m2, const float* v2,
                       float* bn, unsigned* ghist, unsigned* selp, int* selr) {
    int c = threadIdx.x;
    ghist[c] = 0u; ghist[256 + c] = 0u; ghist[512 + c] = 0u; ghist[768 + c] = 0u;
    if (c < 4) { selp[c] = 0u; selr[c] = EE / 2 - 1; }
    if (c < 256) {
        float s = g1[c] / sqrtf(v1[c] + 1e-5f);
        bn[c] = s; bn[256 + c] = be1[c] - m1[c] * s;
    }
    if (c < 128) {
        float s = g2[c] / sqrtf(v2[c] + 1e-5f);
        bn[512 + c] = s; bn[640 + c] = be2[c] - m2[c] * s;
    }
}

// ---------------- per-node u,v,p,q = xn @ {Wa1_top, Wa1_bot, W1a, W1b} ----------------
__global__ void k_uvpq(const float* __restrict__ xn, const float* __restrict__ Wa1,
                       const float* __restrict__ W1, float* __restrict__ uvpq) {
    int chunk = blockIdx.y;
    const float* wbase; int wstride; int ocol;
    switch (chunk) {
        case 0: wbase = Wa1;                 wstride = 128; ocol = 0;   break;
        case 1: wbase = Wa1 + 128 * 128;     wstride = 128; ocol = 128; break;
        case 2: wbase = W1;                  wstride = 256; ocol = 256; break;
        case 3: wbase = W1 + 128;            wstride = 256; ocol = 384; break;
        case 4: wbase = W1 + 128 * 256;      wstride = 256; ocol = 512; break;
        default: wbase = W1 + 128 * 256 + 128; wstride = 256; ocol = 640; break;
    }
    int wv = threadIdx.x >> 6, lane = threadIdx.x & 63;
    int nodebase = blockIdx.x * 32 + wv * 8;
    const float* xrow[8];
#pragma unroll
    for (int j = 0; j < 8; ++j) xrow[j] = xn + (size_t)(nodebase + j) * DDIM;
    float acc0[8] = {}, acc1[8] = {};
#pragma unroll 4
    for (int k = 0; k < 128; ++k) {
        float w0 = wbase[k * wstride + lane];
        float w1 = wbase[k * wstride + 64 + lane];
#pragma unroll
        for (int j = 0; j < 8; ++j) {
            float a = xrow[j][k];
            acc0[j] = fmaf(a, w0, acc0[j]);
            acc1[j] = fmaf(a, w1, acc1[j]);
        }
    }
#pragma unroll
    for (int j = 0; j < 8; ++j) {
        float* orow = uvpq + (size_t)(nodebase + j) * 768 + ocol;
        orow[lane] = acc0[j];
        orow[64 + lane] = acc1[j];
    }
}

// ---------------- fused edge pipeline: lane = edge (64/block), wave = col-stripe ------
// act0/act1: [128][64] activation tiles. Weight rows are wave-uniform -> s_load.
// Per-lane state <= 32 floats, all statically indexed (no scratch).
__global__ __launch_bounds__(512, 4) void
k_edge(const float* __restrict__ xn, const float* __restrict__ uvpq,
       const float* __restrict__ Wa2, const float* __restrict__ ba1,
       const float* __restrict__ ba2, const float* __restrict__ W1,
       const float* __restrict__ b1, const float* __restrict__ W2,
       const float* __restrict__ b2, const float* __restrict__ W3,
       const float* __restrict__ b3, const int* __restrict__ src,
       const int* __restrict__ tgt, const float* __restrict__ bn,
       float* __restrict__ scores) {
    __shared__ float act0[128 * 64];
    __shared__ float act1[128 * 64];
    __shared__ float pmax[8 * 64];   // reused as logit-partial buffer
    __shared__ float pz[8 * 64];
    int tid = threadIdx.x;
    int lane = tid & 63;
    int wvs = (int)__builtin_amdgcn_readfirstlane(tid >> 6);  // wave-uniform
    int b = blockIdx.y;
    int T0 = blockIdx.x * 64;
    int se = src[(size_t)b * EE + T0 + lane];
    int te = tgt[(size_t)b * EE + T0 + lane];
    const float* uv = uvpq + (size_t)b * NN * 768;
    const float* xb = xn + (size_t)b * NN * DDIM;
    const float* up = uv + (size_t)se * 768;
    const float* vp = uv + (size_t)te * 768 + 128;
    int cb = wvs * 16;

    // ---- stage h1 rows [cb, cb+16): h1[k][e] = relu(u_s[k] + v_t[k] + ba1[k])
#pragma unroll
    for (int q = 0; q < 4; ++q) {
        float4 uu = *(const float4*)(up + cb + 4 * q);
        float4 vv = *(const float4*)(vp + cb + 4 * q);
        float4 bv = *(const float4*)(ba1 + cb + 4 * q);   // uniform -> s_load
        act0[(cb + 4 * q + 0) * 64 + lane] = fmaxf(uu.x + vv.x + bv.x, 0.0f);
        act0[(cb + 4 * q + 1) * 64 + lane] = fmaxf(uu.y + vv.y + bv.y, 0.0f);
        act0[(cb + 4 * q + 2) * 64 + lane] = fmaxf(uu.z + vv.z + bv.z, 0.0f);
        act0[(cb + 4 * q + 3) * 64 + lane] = fmaxf(uu.w + vv.w + bv.w, 0.0f);
    }
    __syncthreads();

    // ---- GEMV1: a[i] = sum_k h1[k] * Wa2[k][cb+i] + ba2, i in [0,16)
    float a[16] = {};
    {
        const float* wa = Wa2 + cb;
#pragma unroll 2
        for (int k = 0; k < 128; ++k) {
            float h = act0[k * 64 + lane];
            const float* wr = wa + k * 128;               // uniform row -> s_load
#pragma unroll
            for (int i = 0; i < 16; ++i) a[i] = fmaf(h, wr[i], a[i]);
        }
#pragma unroll
        for (int i = 0; i < 16; ++i) a[i] += ba2[cb + i];
    }
    // ---- softmax: cross-wave reduce via tiny LDS
    {
        float pm = a[0];
#pragma unroll
        for (int i = 1; i < 16; ++i) pm = fmaxf(pm, a[i]);
        pmax[wvs * 64 + lane] = pm;
    }
    __syncthreads();
    float m = pmax[lane];
#pragma unroll
    for (int w = 1; w < 8; ++w) m = fmaxf(m, pmax[w * 64 + lane]);
    float zp = 0.0f;
#pragma unroll
    for (int i = 0; i < 16; ++i) { a[i] = expf(a[i] - m); zp += a[i]; }
    pz[wvs * 64 + lane] = zp;
    __syncthreads();
    float z = pz[lane];
#pragma unroll
    for (int w = 1; w < 8; ++w) z += pz[w * 64 + lane];
    float inv = 1.0f / z;

    // ---- g[c] = |sf-tf|[c] * p[c] * inv -> overwrite act0 rows [cb, cb+16)
#pragma unroll
    for (int q = 0; q < 4; ++q) {
        float4 xs = *(const float4*)(xb + (size_t)se * DDIM + cb + 4 * q);
        float4 xt = *(const float4*)(xb + (size_t)te * DDIM + cb + 4 * q);
        act0[(cb + 4 * q + 0) * 64 + lane] = fabsf(xs.x - xt.x) * a[4 * q + 0] * inv;
        act0[(cb + 4 * q + 1) * 64 + lane] = fabsf(xs.y - xt.y) * a[4 * q + 1] * inv;
        act0[(cb + 4 * q + 2) * 64 + lane] = fabsf(xs.z - xt.z) * a[4 * q + 2] * inv;
        act0[(cb + 4 * q + 3) * 64 + lane] = fabsf(xs.w - xt.w) * a[4 * q + 3] * inv;
    }
    __syncthreads();

    // ---- GEMV2: acc[i] = sum_k g[k] * W1c[k][2cb+i], i in [0,32); then BN1+relu
    float acc[32] = {};
    {
        const float* wc = W1 + 256 * 256 + 2 * cb;
#pragma unroll 2
        for (int k = 0; k < 128; ++k) {
            float g = act0[k * 64 + lane];
            const float* wr = wc + k * 256;               // uniform row -> s_load
#pragma unroll
            for (int i = 0; i < 32; ++i) acc[i] = fmaf(g, wr[i], acc[i]);
        }
    }
    {
        int cB = 2 * cb;
        const float* pr = uv + (size_t)se * 768 + 256 + cB;
        const float* qr = uv + (size_t)te * 768 + 512 + cB;
#pragma unroll
        for (int q = 0; q < 8; ++q) {
            float4 pv = *(const float4*)(pr + 4 * q);
            float4 qv = *(const float4*)(qr + 4 * q);
            float4 bv = *(const float4*)(b1 + cB + 4 * q);   // uniform
            int c0 = cB + 4 * q;
            float y0 = acc[4 * q + 0] + pv.x + qv.x + bv.x;
            float y1 = acc[4 * q + 1] + pv.y + qv.y + bv.y;
            float y2 = acc[4 * q + 2] + pv.z + qv.z + bv.z;
            float y3 = acc[4 * q + 3] + pv.w + qv.w + bv.w;
            acc[4 * q + 0] = fmaxf(fmaf(y0, bn[c0 + 0], bn[256 + c0 + 0]), 0.0f);
            acc[4 * q + 1] = fmaxf(fmaf(y1, bn[c0 + 1], bn[256 + c0 + 1]), 0.0f);
            acc[4 * q + 2] = fmaxf(fmaf(y2, bn[c0 + 2], bn[256 + c0 + 2]), 0.0f);
            acc[4 * q + 3] = fmaxf(fmaf(y3, bn[c0 + 3], bn[256 + c0 + 3]), 0.0f);
        }
    }
    __syncthreads();   // all g reads done; act0/act1 become h2 [256][64]
    {
        float* dst = (wvs < 4) ? act0 : act1;
        int rb = (wvs < 4) ? 2 * cb : 2 * cb - 128;
#pragma unroll
        for (int i = 0; i < 32; ++i) dst[(rb + i) * 64 + lane] = acc[i];
    }
    __syncthreads();

    // ---- GEMV3: a3[i] = sum_k h2[k] * W2[k][cb+i]; BN2+relu; dot W3
    float a3[16] = {};
    {
        const float* w2 = W2 + cb;
#pragma unroll 2
        for (int k = 0; k < 128; ++k) {
            float h = act0[k * 64 + lane];
            const float* wr = w2 + k * 128;
#pragma unroll
            for (int i = 0; i < 16; ++i) a3[i] = fmaf(h, wr[i], a3[i]);
        }
#pragma unroll 2
        for (int k = 0; k < 128; ++k) {
            float h = act1[k * 64 + lane];
            const float* wr = w2 + (k + 128) * 128;
#pragma unroll
            for (int i = 0; i < 16; ++i) a3[i] = fmaf(h, wr[i], a3[i]);
        }
    }
    float ps = 0.0f;
#pragma unroll
    for (int i = 0; i < 16; ++i) {
        int c = cb + i;
        float h3 = fmaxf(fmaf(a3[i] + b2[c], bn[512 + c], bn[640 + c]), 0.0f);
        ps += h3 * W3[c];
    }
    pmax[wvs * 64 + lane] = ps;   // reuse as logit partials
    __syncthreads();
    if (wvs == 0) {
        float lg = pmax[lane];
#pragma unroll
        for (int w = 1; w < 8; ++w) lg += pmax[w * 64 + lane];
        float sc = 1.0f / (1.0f + expf(-(lg + b3[0])));
        scores[(size_t)b * EE + T0 + lane] = sc;
    }
}

// ---------------- parallel radix-select: histogram pass ----------------
__global__ void k_hist(const float* __restrict__ scores, const unsigned* __restrict__ selp,
                       unsigned* __restrict__ ghist, int pass) {
    __shared__ unsigned h[256];
    int b = blockIdx.y;
    h[threadIdx.x] = 0u;
    __syncthreads();
    unsigned pref = selp[b];
    unsigned mask = (pass == 3) ? 0u : (0xFFFFFFFFu << ((pass + 1) * 8));
    const unsigned* sb = (const unsigned*)(scores + (size_t)b * EE);
    int base = blockIdx.x * 2048;
    for (int i = base + threadIdx.x; i < base + 2048; i += 256) {
        unsigned u = sb[i];
        if ((u & mask) == pref) atomicAdd(&h[(u >> (pass * 8)) & 255], 1u);
    }
    __syncthreads();
    unsigned v = h[threadIdx.x];
    if (v) atomicAdd(&ghist[b * 256 + threadIdx.x], v);
}

// ---------------- parallel radix-select: pick digit, reset hist ----------------
__global__ void k_pick(unsigned* __restrict__ ghist, unsigned* __restrict__ selp,
                       int* __restrict__ selr, float* __restrict__ thr, int pass) {
    __shared__ unsigned sh[256];
    int b = blockIdx.x;
    unsigned* gh = ghist + b * 256;
    sh[threadIdx.x] = gh[threadIdx.x];
    __syncthreads();
    if (threadIdx.x == 0) {
        unsigned r = (unsigned)selr[b], cum = 0;
        for (int x = 0; x < 256; ++x) {
            unsigned c = sh[x];
            if (cum + c > r) {
                selp[b] |= (unsigned)x << (pass * 8);
                selr[b] = (int)(r - cum);
                break;
            }
            cum += c;
        }
        if (pass == 0) thr[b] = __uint_as_float(selp[b]);
    }
    __syncthreads();
    gh[threadIdx.x] = 0u;
}

// ---------------- threshold + per-group repair + scatter ----------------
__global__ void k_scatter(const float* __restrict__ scores, const float* __restrict__ thr,
                          const int* __restrict__ src, const int* __restrict__ tgt,
                          const int* __restrict__ mep, float* __restrict__ out) {
    int gid = blockIdx.x * 256 + threadIdx.x;
    int b = gid >> 16;
    int lane = threadIdx.x & 63;
    int j = lane & 15;
    float s = scores[gid];
    float t = thr[b];
    bool above = (s >= t);
    unsigned long long bal = __ballot(above);
    int sub = lane >> 4;
    unsigned int mask16 = (unsigned int)((bal >> (sub * 16)) & 0xFFFFull);
    int active = __popc(mask16);
    int rank = 0;
#pragma unroll
    for (int j2 = 0; j2 < 16; ++j2) {
        float sv = __shfl(s, (lane & 48) + j2, 64);
        rank += (sv > s || (sv == s && j2 < j)) ? 1 : 0;
    }
    int me = *mep;
    int need = (active < me) ? min(me - active, DEGQ) : 0;
    bool keep = above || (rank < need);
    float wgt = keep ? s : 0.0f;
    out[(size_t)b * NN * NN + (size_t)src[gid] * NN + tgt[gid]] = wgt;
}

extern "C" void kernel_launch(void* const* d_in, const int* in_sizes, int n_in,
                              void* d_out, int out_size, void* d_ws, size_t ws_size,
                              hipStream_t stream) {
    const float* nf  = (const float*)d_in[0];
    const int*   src = (const int*)d_in[1];
    const int*   tgt = (const int*)d_in[2];
    const float* Wa1 = (const float*)d_in[3];
    const float* ba1 = (const float*)d_in[4];
    const float* Wa2 = (const float*)d_in[5];
    const float* ba2 = (const float*)d_in[6];
    const float* W1  = (const float*)d_in[7];
    const float* b1  = (const float*)d_in[8];
    const float* g1  = (const float*)d_in[9];
    const float* be1 = (const float*)d_in[10];
    const float* m1  = (const float*)d_in[11];
    const float* v1  = (const float*)d_in[12];
    const float* W2  = (const float*)d_in[13];
    const float* b2  = (const float*)d_in[14];
    const float* g2  = (const float*)d_in[15];
    const float* be2 = (const float*)d_in[16];
    const float* m2  = (const float*)d_in[17];
    const float* v2  = (const float*)d_in[18];
    const float* W3  = (const float*)d_in[19];
    const float* b3  = (const float*)d_in[20];
    const int*   mep = (const int*)d_in[21];

    float* ws = (float*)d_ws;
    float*    xn     = ws + WS_XN;
    float*    uvpq   = ws + WS_UVPQ;
    float*    scores = ws + WS_SCORES;
    float*    thrb   = ws + WS_THR;
    unsigned* selp   = (unsigned*)(ws + WS_SELP);
    int*      selr   = (int*)(ws + WS_SELR);
    unsigned* ghist  = (unsigned*)(ws + WS_GHIST);
    float*    bn     = ws + WS_BN;
    float*    out    = (float*)d_out;

    hipMemsetAsync(d_out, 0, (size_t)out_size * sizeof(float), stream);
    k_prep<<<1, 256, 0, stream>>>(g1, be1, m1, v1, g2, be2, m2, v2, bn, ghist, selp, selr);
    k_norm<<<(BB * NN) / 4, 256, 0, stream>>>(nf, xn);
    k_uvpq<<<dim3((BB * NN) / 32, 6), 256, 0, stream>>>(xn, Wa1, W1, uvpq);
    k_edge<<<dim3(EE / 64, BB), 512, 0, stream>>>(xn, uvpq, Wa2, ba1, ba2, W1, b1,
                                                  W2, b2, W3, b3, src, tgt, bn, scores);
    for (int pass = 3; pass >= 0; --pass) {
        k_hist<<<dim3(32, BB), 256, 0, stream>>>(scores, selp, ghist, pass);
        k_pick<<<BB, 256, 0, stream>>>(ghist, selp, selr, thrb, pass);
    }
    k_scatter<<<(BB * EE) / 256, 256, 0, stream>>>(scores, thrb, src, tgt, mep, out);
}